// Round 4
// baseline (18316.769 us; speedup 1.0000x reference)
//
#include <hip/hip_runtime.h>

#define T_LEN 16384
#define NT 1024
#define NBLK 64      // blocks per direction (x2 directions)
#define CPB 16       // columns (fwd) / rows (bwd) per block
#define NTHR 256     // 4 waves
#define MID 8191     // fwd computes alpha_MID (8191 steps); bwd beta_MID (8192 steps)

typedef unsigned long long u64;
typedef unsigned int u32;

// Exchange buffers (proven protocol): [0..NT) even-parity tags, [NT..2NT) odd.
// tagged word = (step_tag << 32) | float_bits; tag+data fused => no fences needed.
__device__ __align__(16) u64 g_fbuf[2 * NT];
__device__ __align__(16) u64 g_bbuf[2 * NT];

__device__ __forceinline__ u64 pack_tag(u32 tag, float v) {
  return ((u64)tag << 32) | (u64)__float_as_uint(v);
}
__device__ __forceinline__ u64 ld_tag(const u64* p) {
  return __hip_atomic_load(p, __ATOMIC_RELAXED, __HIP_MEMORY_SCOPE_AGENT);
}
__device__ __forceinline__ void st_tag(u64* p, u64 v) {
  __hip_atomic_store(p, v, __ATOMIC_RELAXED, __HIP_MEMORY_SCOPE_AGENT);
}
// LDS flag helpers (workgroup scope)
__device__ __forceinline__ int ld_flag(const int* p) {
  return __hip_atomic_load(p, __ATOMIC_ACQUIRE, __HIP_MEMORY_SCOPE_WORKGROUP);
}
__device__ __forceinline__ void st_flag(int* p, int v) {
  __hip_atomic_store(p, v, __ATOMIC_RELEASE, __HIP_MEMORY_SCOPE_WORKGROUP);
}

__global__ __launch_bounds__(1024) void crf_init(const float* __restrict__ emit,
                                                 const float* __restrict__ strans,
                                                 const float* __restrict__ etrans) {
  int tid = threadIdx.x;
  g_fbuf[tid] = pack_tag(0u, strans[tid] + emit[tid]);
  g_bbuf[tid] = pack_tag(0u, etrans[tid] + emit[(T_LEN - 1) * NT + tid]);
}

__global__ __launch_bounds__(1024) void crf_score(const float* __restrict__ emit,
                                                  const int* __restrict__ y,
                                                  const float* __restrict__ trans,
                                                  const float* __restrict__ strans,
                                                  const float* __restrict__ etrans,
                                                  float* __restrict__ ws) {
  int tid = threadIdx.x;
  float local = 0.f;
  for (int t = tid; t < T_LEN; t += 1024) {
    int yt = y[t];
    local += emit[t * NT + yt];
    if (t > 0) local += trans[y[t - 1] * NT + yt];
  }
  if (tid == 0) local += strans[y[0]];
  if (tid == 1023) local += etrans[y[T_LEN - 1]];
#pragma unroll
  for (int o = 32; o; o >>= 1) local += __shfl_xor(local, o);
  __shared__ float sm[16];
  if ((tid & 63) == 0) sm[tid >> 6] = local;
  __syncthreads();
  if (tid == 0) {
    float s = 0.f;
    for (int i = 0; i < 16; ++i) s += sm[i];
    ws[4096] = s;
  }
}

// Blocks [0,64): forward chain. Blocks [64,128): backward chain.
// Quarter-autonomous waves: wave w polls/fills/FMAs only j in [256w,256w+256).
// Cross-wave combine via monotonic LDS flags (no __syncthreads in the loop).
__global__ __launch_bounds__(NTHR, 1) void crf_scan(const float* __restrict__ emit,
                                                    const float* __restrict__ trans) {
  const int tid = threadIdx.x;
  const bool fwd = blockIdx.x < NBLK;
  const int blk = fwd ? blockIdx.x : (blockIdx.x - NBLK);

  const int w = tid >> 6;            // wave / j-quarter owner
  const int ln = tid & 63;           // lane
  const int c = ln & 15;             // GEMV column (local)
  const int s = ln >> 4;             // j-subchunk 0..3 within quarter
  const int col = blk * CPB + c;     // GEMV column (global)
  const int colS = blk * CPB + 4 * w + (ln & 3);   // store column (lanes 0..3)

  u64* buf0 = fwd ? g_fbuf : g_bbuf;
  u64* buf1 = buf0 + NT;
  const int STEPS = fwd ? MID : (T_LEN - 1 - MID);   // 8191 / 8192

  // P fragment: p[4i+x] = exp(trans[j, col]) (fwd) / exp(trans[col, j]) (bwd),
  // j = 256w + 64s + ((4i + 8s) & 63) + x.  Stagger: the 4 distinct float4
  // addresses per wave-read (s=0..3) land on disjoint bank quads.
  float p[64];
  const int jq = (w << 8) + (s << 6);
#pragma unroll
  for (int i = 0; i < 16; ++i) {
    int off = (4 * i + 8 * s) & 63;
#pragma unroll
    for (int x = 0; x < 4; ++x) {
      int jj = jq + off + x;
      float tv = fwd ? trans[jj * NT + col] : trans[col * NT + jj];
      p[4 * i + x] = __expf(tv);
    }
  }

  __shared__ __align__(16) float aS[NT];      // quarter w region is wave-private
  __shared__ float partS[2][4][16];           // [step parity][wave][col]
  __shared__ float wmax[2][4];                // [step parity][wave]
  __shared__ int flagP[4];                    // monotonic: partS[n&1][w] valid
  __shared__ int flagM[4];                    // monotonic: wmax[n&1][w] valid

  // ---- seed: M0 = max over this block's 16 cols of alpha_0; init flags
  if (tid < 4) { flagP[tid] = 0; flagM[tid] = 0; }
  {
    u64 wd = ld_tag(buf0 + col);
    float v = __uint_as_float((u32)wd);
#pragma unroll
    for (int o = 8; o; o >>= 1) v = fmaxf(v, __shfl_xor(v, o));
    if (ln == 0) wmax[0][w] = v;              // flagM[w]=0 covers this slot
  }
  __syncthreads();                            // one-time: publish seeds/flags

  const int i0 = (w << 8) + ln, i1 = i0 + 64, i2 = i0 + 128, i3 = i0 + 192;

  for (int n = 1; n <= STEPS; ++n) {
    u64* bIn  = (n & 1) ? buf0 : buf1;        // holds tag n-1
    u64* bOut = (n & 1) ? buf1 : buf0;        // receives tag n
    const int par = n & 1;

    const int te = fwd ? n : (T_LEN - 1 - n);

    // Issue the quarter's 4 poll words + emit early; they stay in flight
    // through the LDS flag spin below (clobber stops the compiler sinking them).
    u64 w0 = ld_tag(bIn + i0), w1 = ld_tag(bIn + i1);
    u64 w2 = ld_tag(bIn + i2), w3 = ld_tag(bIn + i3);
    float e = emit[te * NT + colS];
    asm volatile("" ::: "memory");

    // M for this step: max over all 16 cols of alpha_{n-1} (same freshness as R2)
    for (;;) {
      int f0 = ld_flag(&flagM[0]), f1 = ld_flag(&flagM[1]);
      int f2 = ld_flag(&flagM[2]), f3 = ld_flag(&flagM[3]);
      if (f0 >= n - 1 && f1 >= n - 1 && f2 >= n - 1 && f3 >= n - 1) break;
    }
    const int mpar = (n - 1) & 1;
    float M = fmaxf(fmaxf(wmax[mpar][0], wmax[mpar][1]),
                    fmaxf(wmax[mpar][2], wmax[mpar][3]));

    // Poll loop (proven shape) on this wave's quarter only.
    const u32 want = (u32)(n - 1);
    for (;;) {
      bool s0 = (u32)(w0 >> 32) != want;
      bool s1 = (u32)(w1 >> 32) != want;
      bool s2 = (u32)(w2 >> 32) != want;
      bool s3 = (u32)(w3 >> 32) != want;
      if (!(s0 | s1 | s2 | s3)) break;
      if (s0) w0 = ld_tag(bIn + i0);
      if (s1) w1 = ld_tag(bIn + i1);
      if (s2) w2 = ld_tag(bIn + i2);
      if (s3) w3 = ld_tag(bIn + i3);
    }
    // Wave-private fill of its own aS quarter — no barrier needed.
    aS[i0] = __expf(__uint_as_float((u32)w0) - M);
    aS[i1] = __expf(__uint_as_float((u32)w1) - M);
    aS[i2] = __expf(__uint_as_float((u32)w2) - M);
    aS[i3] = __expf(__uint_as_float((u32)w3) - M);

    // GEMV over this quarter: 16 broadcast float4 reads + 64 FMA
    float sacc = 0.f;
    const float4* aV = (const float4*)aS;
#pragma unroll
    for (int i = 0; i < 16; ++i) {
      int off = (4 * i + 8 * s) & 63;
      float4 a4 = aV[(jq + off) >> 2];
      sacc = fmaf(a4.x, p[4 * i + 0], sacc);
      sacc = fmaf(a4.y, p[4 * i + 1], sacc);
      sacc = fmaf(a4.z, p[4 * i + 2], sacc);
      sacc = fmaf(a4.w, p[4 * i + 3], sacc);
    }
    // sum the quarter's 4 s-subchunks (lane bits 4,5)
    sacc += __shfl_xor(sacc, 16);
    sacc += __shfl_xor(sacc, 32);
    if (ln < 16) partS[par][w][c] = sacc;     // one exec-masked ds_write
    st_flag(&flagP[w], n);                    // release: orders the partS write

    // wait for all quarters' partials
    for (;;) {
      int f0 = ld_flag(&flagP[0]), f1 = ld_flag(&flagP[1]);
      int f2 = ld_flag(&flagP[2]), f3 = ld_flag(&flagP[3]);
      if (f0 >= n && f1 >= n && f2 >= n && f3 >= n) break;
    }
    const int cs = 4 * w + (ln & 3);
    float tot = partS[par][0][cs] + partS[par][1][cs] +
                partS[par][2][cs] + partS[par][3][cs];
    float anew = e + M + __logf(tot);
    if (ln < 4) st_tag(bOut + colS, pack_tag((u32)n, anew));  // store ASAP

    // next-step scale: wave-local max over its 4 cols, published via wmax+flagM
    float m2 = anew;
    m2 = fmaxf(m2, __shfl_xor(m2, 1));
    m2 = fmaxf(m2, __shfl_xor(m2, 2));
    if (ln == 0) wmax[par][w] = m2;
    st_flag(&flagM[w], n);                    // release: orders the wmax write
  }
}

__global__ __launch_bounds__(1024) void crf_final(const float* __restrict__ emit,
                                                  const float* __restrict__ ws,
                                                  float* __restrict__ out) {
  int tid = threadIdx.x;
  // alpha_MID: tag 8191 (odd) -> g_fbuf odd half.
  // beta-stream tag 8192 (even) -> g_bbuf even half; stored = beta_MID + emit[MID,:].
  float fa = __uint_as_float((u32)g_fbuf[NT + tid]);
  float bb = __uint_as_float((u32)g_bbuf[tid]);
  float v = fa + bb - emit[MID * NT + tid];   // alpha_MID + beta_MID
  float m = v;
#pragma unroll
  for (int o = 32; o; o >>= 1) m = fmaxf(m, __shfl_xor(m, o));
  __shared__ float sm[16];
  __shared__ float sM;
  if ((tid & 63) == 0) sm[tid >> 6] = m;
  __syncthreads();
  if (tid == 0) {
    float mm = sm[0];
    for (int i = 1; i < 16; ++i) mm = fmaxf(mm, sm[i]);
    sM = mm;
  }
  __syncthreads();
  float Mv = sM;
  float s = __expf(v - Mv);
#pragma unroll
  for (int o = 32; o; o >>= 1) s += __shfl_xor(s, o);
  __shared__ float ss[16];
  if ((tid & 63) == 0) ss[tid >> 6] = s;
  __syncthreads();
  if (tid == 0) {
    float tot = 0.f;
    for (int i = 0; i < 16; ++i) tot += ss[i];
    float logZ = Mv + __logf(tot);
    out[0] = logZ - ws[4096];
  }
}

extern "C" void kernel_launch(void* const* d_in, const int* in_sizes, int n_in,
                              void* d_out, int out_size, void* d_ws, size_t ws_size,
                              hipStream_t stream) {
  const float* emit = (const float*)d_in[0];
  const int* y = (const int*)d_in[1];
  const float* trans = (const float*)d_in[2];
  const float* strans = (const float*)d_in[3];
  const float* etrans = (const float*)d_in[4];
  float* ws = (float*)d_ws;
  float* out = (float*)d_out;

  crf_init<<<1, 1024, 0, stream>>>(emit, strans, etrans);
  crf_score<<<1, 1024, 0, stream>>>(emit, y, trans, strans, etrans, ws);
  crf_scan<<<2 * NBLK, NTHR, 0, stream>>>(emit, trans);
  crf_final<<<1, 1024, 0, stream>>>(emit, ws, out);
}

// Round 5
// 12656.872 us; speedup vs baseline: 1.4472x; 1.4472x over previous
//
#include <hip/hip_runtime.h>

#define T_LEN 16384
#define NT 1024
#define NBLK 64      // blocks per direction (x2 directions)
#define CPB 16       // columns (fwd) / rows (bwd) per block
#define NTHR 256     // 4 waves
#define MID 8191     // fwd computes alpha_MID (8191 steps); bwd beta_MID (8192 steps)

typedef unsigned long long u64;
typedef unsigned int u32;
typedef __attribute__((ext_vector_type(4))) u32 u32x4;

// Exchange buffers (proven protocol): [0..NT) even-parity tags, [NT..2NT) odd.
// tagged word = (step_tag << 32) | float_bits; tag+data fused => no fences needed.
__device__ __align__(32) u64 g_fbuf[2 * NT];
__device__ __align__(32) u64 g_bbuf[2 * NT];

__device__ __forceinline__ u64 pack_tag(u32 tag, float v) {
  return ((u64)tag << 32) | (u64)__float_as_uint(v);
}
__device__ __forceinline__ u64 ld_tag(const u64* p) {
  return __hip_atomic_load(p, __ATOMIC_RELAXED, __HIP_MEMORY_SCOPE_AGENT);
}
__device__ __forceinline__ void st_tag(u64* p, u64 v) {
  __hip_atomic_store(p, v, __ATOMIC_RELAXED, __HIP_MEMORY_SCOPE_AGENT);
}

// Batched device-scope poll: 4 contiguous tagged words (32B) in 2 dwordx4 loads.
// sc0 (bypass L1) + sc1 (bypass L2) = same coherence point (MALL) as the
// agent-scope atomic path; R1's staleness bug was the missing sc1.
// Per-word 8B atomicity is all we need — tags validate each word independently.
__device__ __forceinline__ void ld8_dev(const u64* q, u32x4& A, u32x4& B) {
  asm volatile("global_load_dwordx4 %0, %2, off sc0 sc1\n\t"
               "global_load_dwordx4 %1, %2, off offset:16 sc0 sc1\n\t"
               "s_waitcnt vmcnt(0)"
               : "=&v"(A), "=&v"(B)
               : "v"(q)
               : "memory");
}

__global__ __launch_bounds__(1024) void crf_init(const float* __restrict__ emit,
                                                 const float* __restrict__ strans,
                                                 const float* __restrict__ etrans) {
  int tid = threadIdx.x;
  g_fbuf[tid] = pack_tag(0u, strans[tid] + emit[tid]);
  g_bbuf[tid] = pack_tag(0u, etrans[tid] + emit[(T_LEN - 1) * NT + tid]);
}

__global__ __launch_bounds__(1024) void crf_score(const float* __restrict__ emit,
                                                  const int* __restrict__ y,
                                                  const float* __restrict__ trans,
                                                  const float* __restrict__ strans,
                                                  const float* __restrict__ etrans,
                                                  float* __restrict__ ws) {
  int tid = threadIdx.x;
  float local = 0.f;
  for (int t = tid; t < T_LEN; t += 1024) {
    int yt = y[t];
    local += emit[t * NT + yt];
    if (t > 0) local += trans[y[t - 1] * NT + yt];
  }
  if (tid == 0) local += strans[y[0]];
  if (tid == 1023) local += etrans[y[T_LEN - 1]];
#pragma unroll
  for (int o = 32; o; o >>= 1) local += __shfl_xor(local, o);
  __shared__ float sm[16];
  if ((tid & 63) == 0) sm[tid >> 6] = local;
  __syncthreads();
  if (tid == 0) {
    float s = 0.f;
    for (int i = 0; i < 16; ++i) s += sm[i];
    ws[4096] = s;
  }
}

// Blocks [0,64): forward chain. Blocks [64,128): backward chain.
// Per-step body is the verified R2 schedule; only the consumer poll is
// batched (2x dwordx4 sc0 sc1 on 4 contiguous words per thread).
__global__ __launch_bounds__(NTHR, 1) void crf_scan(const float* __restrict__ emit,
                                                    const float* __restrict__ trans) {
  const int tid = threadIdx.x;
  const bool fwd = blockIdx.x < NBLK;
  const int blk = fwd ? blockIdx.x : (blockIdx.x - NBLK);

  const int c = tid & 15;        // local column (fwd) / row (bwd)
  const int chunk = tid >> 4;    // reduction-dim chunk 0..15 (64 each)
  const int col = blk * CPB + c;
  const int wv = tid >> 6;       // wave 0..3

  u64* buf0 = fwd ? g_fbuf : g_bbuf;
  u64* buf1 = buf0 + NT;
  const int STEPS = fwd ? MID : (T_LEN - 1 - MID);   // 8191 / 8192

  // P fragment: fwd: p = exp(trans[j, col]) (column of trans);
  //             bwd: p = exp(trans[col, k]) (row of trans, coalesced).
  // The 8*chunk stagger keeps the 4 distinct LDS lines per wave-read on
  // disjoint bank quads -> conflict-free broadcast reads (unchanged).
  float p[64];
  const int jbase = chunk * 64;
#pragma unroll
  for (int i = 0; i < 16; ++i) {
    int off = (4 * i + 8 * chunk) & 63;
#pragma unroll
    for (int x = 0; x < 4; ++x) {
      int jj = jbase + off + x;
      float tv = fwd ? trans[jj * NT + col] : trans[col * NT + jj];
      p[4 * i + x] = __expf(tv);
    }
  }

  __shared__ __align__(16) float aS[NT];
  __shared__ float partS[64];    // [wave][16 cols]

  // initial block-local scale M = max over this block's 16 seed values
  float M;
  {
    u64 wd = ld_tag(buf0 + col);
    float v = __uint_as_float((u32)wd);
#pragma unroll
    for (int o = 8; o; o >>= 1) v = fmaxf(v, __shfl_xor(v, o));
    M = v;
  }

  for (int n = 1; n <= STEPS; ++n) {
    u64* bIn  = (n & 1) ? buf0 : buf1;   // holds tag n-1
    u64* bOut = (n & 1) ? buf1 : buf0;   // receives tag n

    const int te = fwd ? n : (T_LEN - 1 - n);
    float e = emit[te * NT + col];       // issued before the poll; overlaps it

    // Batched poll: this thread's 4 contiguous words [4*tid, 4*tid+4).
    // Each thread depends on exactly one producer block -> early spin exit.
    const u32 want = (u32)(n - 1);
    const u64* q = bIn + (tid << 2);
    u32x4 A, B;
    for (;;) {
      ld8_dev(q, A, B);
      if (!((A.y ^ want) | (A.w ^ want) | (B.y ^ want) | (B.w ^ want))) break;
    }
    float4 av;
    av.x = __expf(__uint_as_float(A.x) - M);
    av.y = __expf(__uint_as_float(A.z) - M);
    av.z = __expf(__uint_as_float(B.x) - M);
    av.w = __expf(__uint_as_float(B.z) - M);
    ((float4*)aS)[tid] = av;             // one contiguous ds_write_b128
    __syncthreads();

    // GEMV: thread owns (c, chunk): 16 broadcast float4 reads + 64 FMA
    float s = 0.f;
    const float4* aV = (const float4*)aS;
#pragma unroll
    for (int i = 0; i < 16; ++i) {
      int off = (4 * i + 8 * chunk) & 63;
      float4 a4 = aV[(jbase + off) >> 2];
      s = fmaf(a4.x, p[4 * i + 0], s);
      s = fmaf(a4.y, p[4 * i + 1], s);
      s = fmaf(a4.z, p[4 * i + 2], s);
      s = fmaf(a4.w, p[4 * i + 3], s);
    }
    // reduce over the wave's 4 chunks (tid bits 4,5)
    s += __shfl_xor(s, 16);
    s += __shfl_xor(s, 32);
    if ((tid & 63) < 16) partS[wv * 16 + c] = s;
    __syncthreads();

    // final cross-wave combine, done redundantly by every thread (4 LDS reads)
    float tot = partS[c] + partS[16 + c] + partS[32 + c] + partS[48 + c];
    float anew = e + M + __logf(tot);
    // single coalesced 128B store from one wave (proven R2 shape — do not fragment)
    if (tid < 16) st_tag(bOut + col, pack_tag((u32)n, anew));

    // block-local M for next step: max over this block's 16 fresh values
    float m2 = anew;
#pragma unroll
    for (int o = 8; o; o >>= 1) m2 = fmaxf(m2, __shfl_xor(m2, o));
    M = m2;
  }
}

__global__ __launch_bounds__(1024) void crf_final(const float* __restrict__ emit,
                                                  const float* __restrict__ ws,
                                                  float* __restrict__ out) {
  int tid = threadIdx.x;
  // alpha_MID: tag 8191 (odd) -> g_fbuf odd half.
  // beta-stream tag 8192 (even) -> g_bbuf even half; stored = beta_MID + emit[MID,:].
  float fa = __uint_as_float((u32)g_fbuf[NT + tid]);
  float bb = __uint_as_float((u32)g_bbuf[tid]);
  float v = fa + bb - emit[MID * NT + tid];   // alpha_MID + beta_MID
  float m = v;
#pragma unroll
  for (int o = 32; o; o >>= 1) m = fmaxf(m, __shfl_xor(m, o));
  __shared__ float sm[16];
  __shared__ float sM;
  if ((tid & 63) == 0) sm[tid >> 6] = m;
  __syncthreads();
  if (tid == 0) {
    float mm = sm[0];
    for (int i = 1; i < 16; ++i) mm = fmaxf(mm, sm[i]);
    sM = mm;
  }
  __syncthreads();
  float Mv = sM;
  float s = __expf(v - Mv);
#pragma unroll
  for (int o = 32; o; o >>= 1) s += __shfl_xor(s, o);
  __shared__ float ss[16];
  if ((tid & 63) == 0) ss[tid >> 6] = s;
  __syncthreads();
  if (tid == 0) {
    float tot = 0.f;
    for (int i = 0; i < 16; ++i) tot += ss[i];
    float logZ = Mv + __logf(tot);
    out[0] = logZ - ws[4096];
  }
}

extern "C" void kernel_launch(void* const* d_in, const int* in_sizes, int n_in,
                              void* d_out, int out_size, void* d_ws, size_t ws_size,
                              hipStream_t stream) {
  const float* emit = (const float*)d_in[0];
  const int* y = (const int*)d_in[1];
  const float* trans = (const float*)d_in[2];
  const float* strans = (const float*)d_in[3];
  const float* etrans = (const float*)d_in[4];
  float* ws = (float*)d_ws;
  float* out = (float*)d_out;

  crf_init<<<1, 1024, 0, stream>>>(emit, strans, etrans);
  crf_score<<<1, 1024, 0, stream>>>(emit, y, trans, strans, etrans, ws);
  crf_scan<<<2 * NBLK, NTHR, 0, stream>>>(emit, trans);
  crf_final<<<1, 1024, 0, stream>>>(emit, ws, out);
}